// Round 17
// baseline (334.481 us; speedup 1.0000x reference)
//
#include <hip/hip_runtime.h>
#include <hip/hip_bf16.h>
#include <math.h>

#define NT 512   // 8 waves
#define EB 16    // edges per block (2 per wave in phase 1)

using sv4    = __attribute__((ext_vector_type(4))) short;
using short8 = __attribute__((ext_vector_type(8))) short;
using f32x4  = __attribute__((ext_vector_type(4))) float;
using f32x2  = __attribute__((ext_vector_type(2))) float;
typedef unsigned short u16;
typedef unsigned int   u32;

#define MFMA(a,b,c) __builtin_amdgcn_mfma_f32_16x16x32_bf16((a),(b),(c),0,0,0)

// ---- swizzled-weight fragment table (each frag = 64 lanes x 8 bf16 = 1024B)
#define FW0   0
#define FW1R  150
#define FW1I  165
#define FW1IN 180
#define FW2R  195
#define FW2I  197
#define FW2IN 199
#define FL0   201
#define FL1   209
#define FL2   211
#define NFRAG 212
#define WS_NLS_OFF ((size_t)NFRAG * 512)   // u16 elements

// fast bf16 convert: round-half-up, no NaN path (inputs finite) — 2 VALU ops
__device__ __forceinline__ u16 f2b(float x) {
  union { float f; u32 u; } v; v.f = x;
  return (u16)((v.u + 0x8000u) >> 16);
}
__device__ __forceinline__ float b2f(u16 u) {
  union { float f; u32 u; } v; v.u = ((u32)u) << 16;
  return v.f;
}
__device__ __forceinline__ sv4 ld4(const u16* p){ return *reinterpret_cast<const sv4*>(p); }

// ---------------- weight pre-swizzle ------------------------------------------
__global__ void prep_w(const float* __restrict__ w0,
                       const float* __restrict__ w1r, const float* __restrict__ w1i,
                       const float* __restrict__ w2r, const float* __restrict__ w2i,
                       const float* __restrict__ l0,  const float* __restrict__ l1,
                       const float* __restrict__ l2,  u16* __restrict__ ws) {
  const int g = blockIdx.x * 256 + threadIdx.x;
  if (g >= NFRAG * 64) return;
  const int frag = g >> 6, lane = g & 63;
  const float* src; int K, N, kt, nt; float sgn = 1.f;
  if (frag < FW1R)       { src = w0;  K = 464; N = 160; int f = frag;       kt = f/10; nt = f%10; }
  else if (frag < FW1I)  { src = w1r; K = 144; N = 48;  int f = frag-FW1R;  kt = f/3;  nt = f%3; }
  else if (frag < FW1IN) { src = w1i; K = 144; N = 48;  int f = frag-FW1I;  kt = f/3;  nt = f%3; }
  else if (frag < FW2R)  { src = w1i; K = 144; N = 48;  int f = frag-FW1IN; kt = f/3;  nt = f%3; sgn = -1.f; }
  else if (frag < FW2I)  { src = w2r; K = 48;  N = 16;  kt = frag-FW2R; nt = 0; }
  else if (frag < FW2IN) { src = w2i; K = 48;  N = 16;  kt = frag-FW2I; nt = 0; }
  else if (frag < FL0)   { src = w2i; K = 48;  N = 16;  kt = frag-FW2IN; nt = 0; sgn = -1.f; }
  else if (frag < FL1)   { src = l0;  K = 64;  N = 64;  int f = frag-FL0;   kt = f/4;  nt = f%4; }
  else if (frag < FL2)   { src = l1;  K = 32;  N = 32;  kt = 0; nt = frag-FL1; }
  else                   { src = l2;  K = 16;  N = 16;  kt = 0; nt = 0; }
  const int n  = nt*16 + (lane & 15);
  const int k0 = kt*32 + (lane >> 4) * 8;
  u16* dst = ws + (size_t)frag * 512 + lane * 8;
  #pragma unroll
  for (int j = 0; j < 8; ++j) {
    const int k = k0 + j;
    const float v = (k < K && n < N) ? src[k * N + n] * sgn : 0.f;
    dst[j] = f2b(v);
  }
}

// ---------------- node pre-LN: f32[N][240] -> packed bf16[N][320] -------------
__global__ void ln_nodes(const float* __restrict__ rows,
                         const float* __restrict__ w0, const float* __restrict__ b0,
                         const float* __restrict__ w1, const float* __restrict__ w2,
                         u16* __restrict__ tab, int R) {
  const int row  = blockIdx.x * 4 + (threadIdx.x >> 6);
  const int lane = threadIdx.x & 63;
  if (row >= R) return;
  const float* src = rows + (size_t)row * 240;
  const float v0 = src[lane];
  const float v1 = src[lane + 64];
  const float v2 = src[lane + 128];
  const float v3 = (lane < 48) ? src[lane + 192] : 0.f;
  const bool lo = (lane < 32);
  float sm = v0, sq = v0*v0;
  float Sc = v1*v1*(1.f/192.f) + v2*v2*(lo ? (1.f/192.f) : (1.f/160.f)) + v3*v3*(1.f/160.f);
  #pragma unroll
  for (int s = 32; s > 0; s >>= 1) {
    sm += __shfl_xor(sm, s, 64); sq += __shfl_xor(sq, s, 64);
    Sc += __shfl_xor(Sc, s, 64);
  }
  const float mu  = sm * (1.f/64.f);
  const float i0  = rsqrtf(sq*(1.f/64.f) - mu*mu + 1e-8f);
  const float inv = rsqrtf(Sc + 1e-8f);
  u16* dst = tab + (size_t)row * 320;
  dst[lane] = f2b((v0 - mu) * i0 * w0[lane] + b0[lane]);
  { const int u = lane;      const int c = u/3, j = u-3*c; dst[64 + 4*c + j]  = f2b(v1*inv*w1[c]); }
  if (lo) { const int u = lane+64; const int c = u/3, j = u-3*c; dst[64 + 4*c + j]  = f2b(v2*inv*w1[c]); }
  else    { const int u = lane-32; const int c = u/5, j = u-5*c; dst[192 + 8*c + j] = f2b(v2*inv*w2[c]); }
  if (lane < 48) { const int u = lane+32; const int c = u/5, j = u-5*c; dst[192 + 8*c + j] = f2b(v3*inv*w2[c]); }
  if (lane < 32) dst[64 + 4*lane + 3] = 0;
  if (lane < 48) { const int c = lane/3, j = lane-3*c; dst[192 + 8*c + 5 + j] = 0; }
}

// ------------------------------ main fused kernel -----------------------------
// LDS layout (bytes), total 38848 -> 4 blocks/CU (8 waves each):
//  0     m0  u16[16x472+8]=15120 | o0f f32[16][172]@0 (cols 112-159 only used)
//                                | g1s 3x[16x40]u16 @11008 ; yt f32[16][64]@0 (post-B5)
//  15120 p1  u16[16x152+8]=4880  | op1f f32[16][52] ; ot f32[16][176] @15120
//  20000 n1  u16[16x152+8]=4880  | on1f
//  24880 p2  u16[16x56+8]=1808   | op2f
//  26688 n2  u16[16x56+8]=1808   | on2f
//  28496 scratch: scr f32[8][176] (phase1) | gates@28496 + scs@30032 (post-B3)
//        + g2s 5x[16x24+8]u16 @32336 (post-B4)
//  36256 Dc  f32[16x40+8]=2592
__global__ __launch_bounds__(NT, 4)
void iel_mfma(const float* __restrict__ latents,
              const float* __restrict__ edgef,
              const float* __restrict__ wig,
              const float* __restrict__ ln_e_w0, const float* __restrict__ ln_e_b0,
              const float* __restrict__ ln_e_w1, const float* __restrict__ ln_e_w2,
              const float* __restrict__ lp_b0,
              const int* __restrict__ edge_index, const int* __restrict__ active_edges,
              const u16* __restrict__ ws, const u16* __restrict__ nls,
              float* __restrict__ out,
              int Etot, int A)
{
  __shared__ __align__(16) char SMEM[38848];
  u16*   m0   = (u16*)(SMEM);
  u16*   p1   = (u16*)(SMEM + 15120);
  u16*   n1   = (u16*)(SMEM + 20000);
  u16*   p2   = (u16*)(SMEM + 24880);
  u16*   n2   = (u16*)(SMEM + 26688);
  float* scr  = (float*)(SMEM + 28496);
  float* Dc   = (float*)(SMEM + 36256);
  u16*   g2s  = (u16*)(SMEM + 32336);
  float* o0f  = (float*)(SMEM);           // stride 172; only cols 112-159 live
  u16*   g1s  = (u16*)(SMEM + 11008);
  float* op1f = (float*)(SMEM + 15120);
  float* on1f = (float*)(SMEM + 20000);
  float* op2f = (float*)(SMEM + 24880);
  float* on2f = (float*)(SMEM + 26688);
  u16*   gates= (u16*)(SMEM + 28496);
  u16*   scs  = (u16*)(SMEM + 30032);
  float* ot   = (float*)(SMEM + 15120);
  float* yt   = (float*)(SMEM);

  const short8* WF = (const short8*)ws;
  const int t    = threadIdx.x;
  const int lane = t & 63;
  const int w    = t >> 6;                // 0..7
  const int eb0  = blockIdx.x * EB;
  const f32x4 Z4 = {0.f, 0.f, 0.f, 0.f};

  // ---- lane class: 0 = l1 triple, 1 = l2 quint i=0..2, 2 = quint i=3..4
  const int cls = (lane < 32) ? 0 : ((lane < 48) ? 1 : 2);
  const int cc  = (cls == 0) ? lane : (lane & 15);
  const int dbase = (cls == 0) ? 1 : ((cls == 1) ? 12 : 27);
  const int dstr  = (cls == 0) ? 3 : 5;

  // ---- edge-LN staging factors ----
  const int c1 = lane / 3;
  const bool q2lo = (lane < 32);
  const int c2 = q2lo ? (lane + 64) / 3 : (lane - 32) / 5;
  const int c3 = (lane < 48) ? (lane + 32) / 5 : 15;
  const float w0e = ln_e_w0[lane], b0e = ln_e_b0[lane];
  const float wAe = ln_e_w1[c1];
  const float wBe = q2lo ? ln_e_w1[c2] : ln_e_w2[c2];
  const float wCe = ln_e_w2[c3];
  float* swr = scr + w * 176;

  // ---- edge index prefetch (wave's 2 edges) ----
  int aev[2], ecv[2], env[2];
  #pragma unroll
  for (int it = 0; it < 2; ++it) {
    const int e = eb0 + (w<<1) + it;
    aev[it] = active_edges[(e < A) ? e : (A-1)];
  }
  #pragma unroll
  for (int it = 0; it < 2; ++it) {
    ecv[it] = edge_index[aev[it]];
    env[it] = edge_index[Etot + aev[it]];
  }

  struct ER {
    u16 q0a, q0b, x4a, x4b;
    sv4 xa, xb;
    float e0, e1, e2, e3, l0, l1;
  };
  ER RA, RB;
  const int xoff = (cls == 0) ? (64 + 4*lane) : (192 + 8*cc);

  auto issue = [&](int it, ER& R) {
    const int e  = eb0 + (w<<1) + it;
    const int eS = (e < A) ? e : (A-1);
    const u16* nba = nls + (size_t)ecv[it]*320;
    const u16* nbb = nls + (size_t)env[it]*320;
    R.q0a = nba[lane]; R.q0b = nbb[lane];
    R.xa = ld4(nba + xoff); R.xb = ld4(nbb + xoff);
    R.x4a = (cls == 0) ? (u16)0 : nba[xoff + 4];
    R.x4b = (cls == 0) ? (u16)0 : nbb[xoff + 4];
    const float* ep = edgef + (size_t)eS*240;
    R.e0 = ep[lane]; R.e1 = ep[lane+64]; R.e2 = ep[lane+128];
    R.e3 = (lane < 48) ? ep[lane+192] : 0.f;
    const float* lr = latents + (size_t)aev[it]*128;
    R.l0 = lr[lane]; R.l1 = lr[64+lane];
  };

  // ---- ISSUE FIRST: get the deep gather chain in flight ----
  issue(0, RA);
  issue(1, RB);

  // ---- pad/tail clear while gathers are in flight ----
  if (t < 256) {
    const int r = t >> 4, c = t & 15;
    if (c < 8) {
      m0[r*472 + 464 + c] = 0;
      p1[r*152 + 144 + c] = 0;
      n1[r*152 + 144 + c] = 0;
      p2[r*56  + 48  + c] = 0;
      n2[r*56  + 48  + c] = 0;
    }
    if (t < 8) {
      m0[16*472 + t] = 0;
      p1[16*152 + t] = 0;
      n1[16*152 + t] = 0;
      p2[16*56  + t] = 0;
      n2[16*56  + t] = 0;
    }
  }

  // ---- stage compact Wigner D (stride 40); zero slots 10/11 -----------------
  #pragma unroll
  for (int it = 0; it < 2; ++it) {
    const int el = (w<<1) + it;
    const int e  = eb0 + el;
    const int eS = (e < A) ? e : (A-1);
    if (lane < 35) {
      int src, dst;
      if (lane == 0)      { src = 0; dst = 0; }
      else if (lane < 10) { const int a=(lane-1)/3, b=(lane-1)-3*((lane-1)/3); src=(1+a)*9+(1+b); dst=lane; }
      else                { const int a=(lane-10)/5, b=(lane-10)-5*((lane-10)/5); src=(4+a)*9+(4+b); dst=lane+2; }
      Dc[el*40 + dst] = wig[(size_t)eS*81 + src];
    } else if (lane < 37) {
      Dc[el*40 + (lane - 25)] = 0.f;   // slots 10,11 (x-padding, must be 0.0)
    }
  }

  auto process = [&](int it, ER& R) {
    const int el = (w<<1) + it;
    const float* DcE = Dc + el*40;
    const float d00 = DcE[0];
    float d[3][5];
    #pragma unroll
    for (int i = 0; i < 3; ++i)
      #pragma unroll
      for (int j = 0; j < 5; ++j)
        d[i][j] = DcE[dbase + i*dstr + j];

    u16* B0; u16* B1; u16* B2; int S0, S1, S2;
    if (cls == 0)      { B0 = n1 + el*152 + cc;      S0 = 48;  B1 = m0 + el*472 + 64 + cc; S1 = 112; B2 = p1 + el*152 + cc;      S2 = 48; }
    else if (cls == 1) { B0 = n2 + el*56  + cc;      S0 = 16;  B1 = n1 + el*152 + 32 + cc; S1 = 48;  B2 = m0 + el*472 + 96 + cc; S2 = 112; }
    else               { B0 = p1 + el*152 + 32 + cc; S0 = 48;  B1 = p2 + el*56  + cc;      S1 = 16;  B2 = m0;                    S2 = 0; }

    // node rows r=0 (ec) and r=2 (en) — paired via packed f32x2 math
    {
      f32x2 x0 = {b2f((u16)R.xa[0]), b2f((u16)R.xb[0])};
      f32x2 x1 = {b2f((u16)R.xa[1]), b2f((u16)R.xb[1])};
      f32x2 x2 = {b2f((u16)R.xa[2]), b2f((u16)R.xb[2])};
      f32x2 x3 = {b2f((u16)R.xa[3]), b2f((u16)R.xb[3])};
      f32x2 x4 = {b2f(R.x4a), b2f(R.x4b)};
      f32x2 q0 = {b2f(R.q0a), b2f(R.q0b)};
      f32x2 q0d = q0 * d00;
      m0[el*472 + lane]       = f2b(q0d[0]);
      m0[el*472 + 224 + lane] = f2b(q0d[1]);
      f32x2 s0 = x0*d[0][0] + x1*d[0][1] + x2*d[0][2] + x3*d[0][3] + x4*d[0][4];
      f32x2 s1 = x0*d[1][0] + x1*d[1][1] + x2*d[1][2] + x3*d[1][3] + x4*d[1][4];
      f32x2 s2 = x0*d[2][0] + x1*d[2][1] + x2*d[2][2] + x3*d[2][3] + x4*d[2][4];
      B0[0] = f2b(s0[0]); B0[2*S0] = f2b(s0[1]);
      B1[0] = f2b(s1[0]); B1[2*S1] = f2b(s1[1]);
      if (lane < 48) { B2[0] = f2b(s2[0]); B2[2*S2] = f2b(s2[1]); }
    }

    // edge row r=1: LN (3-sum reduction) + rotation
    {
      const float v0 = R.e0, v1 = R.e1, v2 = R.e2, v3 = R.e3;
      float sm = v0, sq = v0*v0;
      float Sc = v1*v1*(1.f/192.f) + v2*v2*(q2lo ? (1.f/192.f) : (1.f/160.f))
               + v3*v3*(1.f/160.f);
      #pragma unroll
      for (int s = 32; s > 0; s >>= 1) {
        sm += __shfl_xor(sm, s, 64);  sq += __shfl_xor(sq, s, 64);
        Sc += __shfl_xor(Sc, s, 64);
      }
      const float mu = sm * (1.f/64.f);
      const float i0 = rsqrtf(sq*(1.f/64.f) - mu*mu + 1e-8f);
      const float iv = rsqrtf(Sc + 1e-8f);
      swr[lane]      = v1 * iv * wAe;
      swr[64 + lane] = v2 * iv * wBe;
      if (lane < 48) swr[128 + lane] = v3 * iv * wCe;
      asm volatile("s_waitcnt lgkmcnt(0)" ::: "memory");
      m0[el*472 + 112 + lane] = f2b(((v0 - mu)*i0*w0e + b0e) * d00);
      const float* sb = (cls == 0) ? (swr + 3*cc) : (swr + 96 + 5*cc);
      const float x0 = sb[0], x1 = sb[1], x2 = sb[2];
      const float x3 = (cls == 0) ? 0.f : sb[3];
      const float x4 = (cls == 0) ? 0.f : sb[4];
      float s0v = d[0][0]*x0 + d[0][1]*x1 + d[0][2]*x2 + d[0][3]*x3 + d[0][4]*x4;
      float s1v = d[1][0]*x0 + d[1][1]*x1 + d[1][2]*x2 + d[1][3]*x3 + d[1][4]*x4;
      float s2v = d[2][0]*x0 + d[2][1]*x1 + d[2][2]*x2 + d[2][3]*x3 + d[2][4]*x4;
      B0[S0] = f2b(s0v);
      B1[S1] = f2b(s1v);
      if (lane < 48) B2[S2] = f2b(s2v);
    }
    m0[el*472 + 336 + lane] = f2b(R.l0);
    m0[el*472 + 400 + lane] = f2b(R.l1);
  };

  process(0, RA);
  process(1, RB);
  __syncthreads();  // B2: features + Dc ready

  // ---- Phase 2 (balanced): 2a tile w for all; extra tiles 8,9 -> waves 6,7;
  //      2b tasks -> waves 0-5; 2c tasks -> waves 0,1 ------------------------
  f32x4 acc2a[2] = {Z4, Z4};
  {
    const u16* abase = m0 + (lane & 15)*472 + (lane >> 4)*8;
    #pragma unroll
    for (int kt = 0; kt < 15; ++kt) {
      const short8 a = *reinterpret_cast<const short8*>(abase + kt*32);
      acc2a[0] = MFMA(a, WF[(size_t)(FW0 + kt*10 + w)*64 + lane], acc2a[0]);
      if (w >= 6)
        acc2a[1] = MFMA(a, WF[(size_t)(FW0 + kt*10 + (w+2))*64 + lane], acc2a[1]);
    }
  }
  f32x4 acc2b = Z4;
  f32x4 acc2c = Z4;
  if (w < 6) {
    const u16* pbase = p1 + (lane & 15)*152 + (lane >> 4)*8;
    const u16* nbase = n1 + (lane & 15)*152 + (lane >> 4)*8;
    const int isOn = (w >= 3) ? 1 : 0;
    const int nt2 = w - 3*isOn;
    #pragma unroll
    for (int kt = 0; kt < 5; ++kt) {
      const short8 pa = *reinterpret_cast<const short8*>(pbase + kt*32);
      const short8 na = *reinterpret_cast<const short8*>(nbase + kt*32);
      acc2b = MFMA(pa, WF[(size_t)((isOn?FW1I:FW1R)  + kt*3 + nt2)*64 + lane], acc2b);
      acc2b = MFMA(na, WF[(size_t)((isOn?FW1R:FW1IN) + kt*3 + nt2)*64 + lane], acc2b);
    }
  }
  if (w < 2) {
    const u16* pb2 = p2 + (lane & 15)*56 + (lane >> 4)*8;
    const u16* nb2 = n2 + (lane & 15)*56 + (lane >> 4)*8;
    const int isOn2 = (w == 1);
    #pragma unroll
    for (int kt = 0; kt < 2; ++kt) {
      const short8 pa = *reinterpret_cast<const short8*>(pb2 + kt*32);
      const short8 na = *reinterpret_cast<const short8*>(nb2 + kt*32);
      acc2c = MFMA(pa, WF[(size_t)((isOn2?FW2I:FW2R)  + kt)*64 + lane], acc2c);
      acc2c = MFMA(na, WF[(size_t)((isOn2?FW2R:FW2IN) + kt)*64 + lane], acc2c);
    }
  }
  __syncthreads();  // B3: all feature reads done (scr dead since B2)

  // ---- Write phase: silu/gates DIRECT from acc2a (cols 0-111);
  //      o0f only for cols 112-159; op/on writes; g2s pad clear --------------
  {
    const int col = w*16 + (lane & 15);
    const int r0  = (lane >> 4)*4;
    if (w < 7) {
      // cols 0-111: silu (cols<64) or gates (64-111), computed in-register
      #pragma unroll
      for (int j = 0; j < 4; ++j) {
        const int row = r0 + j;
        const float x = acc2a[0][j] * 0.046423835f * Dc[row*40];
        const float sg = 1.f/(1.f + __expf(-x));
        if (w < 4) scs[row*72 + col] = f2b(x * sg);
        else       gates[row*48 + (col - 64)] = f2b(sg);
      }
    } else {
      #pragma unroll
      for (int j = 0; j < 4; ++j)
        o0f[(r0+j)*172 + col] = acc2a[0][j] * 0.046423835f;   // cols 112-127
    }
    if (w >= 6) {
      const int col2 = (w+2)*16 + (lane & 15);                 // cols 128-159
      #pragma unroll
      for (int j = 0; j < 4; ++j)
        o0f[(r0+j)*172 + col2] = acc2a[1][j] * 0.046423835f;
    }
    if (w < 6) {
      const int isOn = (w >= 3) ? 1 : 0;
      const int nt2 = w - 3*isOn;
      float* dst = isOn ? on1f : op1f;
      const int colb = nt2*16 + (lane & 15);
      #pragma unroll
      for (int j = 0; j < 4; ++j)
        dst[(r0+j)*52 + colb] = acc2b[j] * (1.f/12.f);
    }
    if (w < 2) {
      float* dst = (w == 1) ? on2f : op2f;
      #pragma unroll
      for (int j = 0; j < 4; ++j)
        dst[(r0+j)*20 + (lane & 15)] = acc2c[j] * 0.14433757f;  // 1/sqrt(48)
    }
  }
  if (t < 256) {   // g2s pad clear (scr dead)
    const int r = t >> 4, c = t & 15;
    if (c < 8) {
      #pragma unroll
      for (int m = 0; m < 5; ++m) g2s[m*392 + r*24 + 16 + c] = 0;
    }
    if (t < 8) {
      #pragma unroll
      for (int m = 0; m < 5; ++m) g2s[m*392 + 384 + t] = 0;
    }
  }
  __syncthreads();  // B4: o0f(112-159)/op/on/scs/gates ready

  // A2: rotate-back + gate -> g1/g2 bf16 staging
  {
    const int e = t >> 5, l32 = t & 31;
    const float* DcE = Dc + e*40;
    #pragma unroll
    for (int k = 0; k < 3; ++k) {
      const int item = l32 + 32*k;            // 0..95
      const int c = item/3, m = item - 3*c;
      const float val = DcE[1 + m]     * on1f[e*52 + c]
                      + DcE[1 + 3 + m] * o0f[e*172 + 112 + c]
                      + DcE[1 + 6 + m] * op1f[e*52 + c];
      const float g = b2f(gates[e*48 + c]);
      g1s[m*640 + e*40 + c] = f2b(val * g);
    }
    if (l32 < 16) {
      const int c = l32;
      const float f0 = on2f[e*20 + c];
      const float f1 = on1f[e*52 + 32 + c];
      const float f2c = o0f[e*172 + 144 + c];
      const float f3 = op1f[e*52 + 32 + c];
      const float f4 = op2f[e*20 + c];
      const float gg = b2f(gates[e*48 + 32 + c]);
      #pragma unroll
      for (int m = 0; m < 5; ++m) {
        const float val = DcE[12 + m]*f0 + DcE[12 + 5 + m]*f1 + DcE[12 + 10 + m]*f2c
                        + DcE[12 + 15 + m]*f3 + DcE[12 + 20 + m]*f4;
        g2s[m*392 + e*24 + c] = f2b(val * gg);
      }
    }
  }
  __syncthreads();  // B5 (o0f dead -> yt alias valid)

  // ---- Phase 3: final matmuls; all outputs staged (yt + ot) ------------------
  for (int tau = w; tau < 15; tau += 8) {
    const int col16 = lane & 15;
    const int r0 = (lane >> 4)*4;
    if (tau < 4) {            // y0 -> yt cols [0,64)
      const int ntt = tau;
      f32x4 a0 = Z4;
      #pragma unroll
      for (int kt = 0; kt < 2; ++kt) {
        const short8 a = *reinterpret_cast<const short8*>(
            scs + (lane & 15)*72 + kt*32 + (lane >> 4)*8);
        a0 = MFMA(a, WF[(size_t)(FL0 + kt*4 + ntt)*64 + lane], a0);
      }
      const int col = ntt*16 + col16;
      const float bias = lp_b0[col];
      #pragma unroll
      for (int j = 0; j < 4; ++j)
        yt[(r0+j)*64 + col] = a0[j]*0.125f + bias;
    } else if (tau < 10) {    // y1 -> ot cols [0,96)
      const int u = tau - 4, m = u >> 1, ntt = u & 1;
      const short8 a = *reinterpret_cast<const short8*>(
          g1s + m*640 + (lane & 15)*40 + (lane >> 4)*8);
      f32x4 a0 = Z4;
      a0 = MFMA(a, WF[(size_t)(FL1 + ntt)*64 + lane], a0);
      const int oc = (ntt*16 + col16)*3 + m;
      #pragma unroll
      for (int j = 0; j < 4; ++j)
        ot[(r0+j)*176 + oc] = a0[j]*0.17677670f;   // 1/sqrt(32)
    } else {                  // y2 -> ot cols [96,176)
      const int m = tau - 10;
      const short8 a = *reinterpret_cast<const short8*>(
          g2s + m*392 + (lane & 15)*24 + (lane >> 4)*8);
      f32x4 a0 = Z4;
      a0 = MFMA(a, WF[(size_t)FL2*64 + lane], a0);
      const int oc = 96 + col16*5 + m;
      #pragma unroll
      for (int j = 0; j < 4; ++j)
        ot[(r0+j)*176 + oc] = a0[j]*0.25f;         // 1/sqrt(16)
    }
  }
  __syncthreads();  // B6: yt + ot complete

  // single-pass coalesced copy-out: full 240-float rows (60 float4 per row)
  for (int idx = t; idx < 16*60; idx += NT) {
    const int row = idx / 60, seg = idx - row*60;
    const int er = eb0 + row;
    if (er < A) {
      f32x4 v;
      if (seg < 16) v = *reinterpret_cast<const f32x4*>(yt + row*64 + seg*4);
      else          v = *reinterpret_cast<const f32x4*>(ot + row*176 + (seg-16)*4);
      *reinterpret_cast<f32x4*>(out + (size_t)er*240 + seg*4) = v;
    }
  }
}

extern "C" void kernel_launch(void* const* d_in, const int* in_sizes, int n_in,
                              void* d_out, int out_size, void* d_ws, size_t ws_size,
                              hipStream_t stream) {
  const float* latents  = (const float*)d_in[0];
  const float* nodef    = (const float*)d_in[1];
  const float* edgef    = (const float*)d_in[2];
  const float* wig      = (const float*)d_in[4];
  const float* ln_n_w0  = (const float*)d_in[5];
  const float* ln_n_b0  = (const float*)d_in[6];
  const float* ln_n_w1  = (const float*)d_in[7];
  const float* ln_n_w2  = (const float*)d_in[8];
  const float* ln_e_w0  = (const float*)d_in[9];
  const float* ln_e_b0  = (const float*)d_in[10];
  const float* ln_e_w1  = (const float*)d_in[11];
  const float* ln_e_w2  = (const float*)d_in[12];
  const float* so2_w0   = (const float*)d_in[13];
  const float* so2_w1r  = (const float*)d_in[14];
  const float* so2_w1i  = (const float*)d_in[15];
  const float* so2_w2r  = (const float*)d_in[16];
  const float* so2_w2i  = (const float*)d_in[17];
  const float* lp_w0    = (const float*)d_in[18];
  const float* lp_b0    = (const float*)d_in[19];
  const float* lp_w1    = (const float*)d_in[20];
  const float* lp_w2    = (const float*)d_in[21];
  const int*   edge_index   = (const int*)d_in[22];
  const int*   active_edges = (const int*)d_in[23];

  const int Etot = in_sizes[2] / 240;
  const int N    = in_sizes[1] / 240;
  const int A    = in_sizes[23];

  u16* ws  = (u16*)d_ws;
  u16* nls = ws + WS_NLS_OFF;            // node-LN table: N*320 u16

  const int pthreads = NFRAG * 64;
  hipLaunchKernelGGL(prep_w, dim3((pthreads + 255) / 256), dim3(256), 0, stream,
                     so2_w0, so2_w1r, so2_w1i, so2_w2r, so2_w2i,
                     lp_w0, lp_w1, lp_w2, ws);

  hipLaunchKernelGGL(ln_nodes, dim3((N + 3) / 4), dim3(256), 0, stream,
                     nodef, ln_n_w0, ln_n_b0, ln_n_w1, ln_n_w2, nls, N);

  const int grid = (A + EB - 1) / EB;
  hipLaunchKernelGGL(iel_mfma, dim3(grid), dim3(NT), 0, stream,
                     latents, edgef, wig,
                     ln_e_w0, ln_e_b0, ln_e_w1, ln_e_w2,
                     lp_b0, edge_index, active_edges, ws, nls,
                     (float*)d_out, Etot, A);
}

// Round 18
// 329.457 us; speedup vs baseline: 1.0152x; 1.0152x over previous
//
#include <hip/hip_runtime.h>
#include <hip/hip_bf16.h>
#include <math.h>

#define NT 512   // 8 waves
#define EB 16    // edges per block (2 per wave in phase 1)

using sv4    = __attribute__((ext_vector_type(4))) short;
using short8 = __attribute__((ext_vector_type(8))) short;
using f32x4  = __attribute__((ext_vector_type(4))) float;
using f32x2  = __attribute__((ext_vector_type(2))) float;
typedef unsigned short u16;
typedef unsigned int   u32;

#define MFMA(a,b,c) __builtin_amdgcn_mfma_f32_16x16x32_bf16((a),(b),(c),0,0,0)

// ---- swizzled-weight fragment table (each frag = 64 lanes x 8 bf16 = 1024B)
#define FW0   0
#define FW1R  150
#define FW1I  165
#define FW1IN 180
#define FW2R  195
#define FW2I  197
#define FW2IN 199
#define FL0   201
#define FL1   209
#define FL2   211
#define NFRAG 212
#define WS_NLS_OFF ((size_t)NFRAG * 512)   // u16 elements

// fast bf16 convert: round-half-up, no NaN path (inputs finite) — 2 VALU ops
__device__ __forceinline__ u16 f2b(float x) {
  union { float f; u32 u; } v; v.f = x;
  return (u16)((v.u + 0x8000u) >> 16);
}
__device__ __forceinline__ float b2f(u16 u) {
  union { float f; u32 u; } v; v.u = ((u32)u) << 16;
  return v.f;
}
__device__ __forceinline__ sv4 ld4(const u16* p){ return *reinterpret_cast<const sv4*>(p); }

// ---------------- weight pre-swizzle ------------------------------------------
__global__ void prep_w(const float* __restrict__ w0,
                       const float* __restrict__ w1r, const float* __restrict__ w1i,
                       const float* __restrict__ w2r, const float* __restrict__ w2i,
                       const float* __restrict__ l0,  const float* __restrict__ l1,
                       const float* __restrict__ l2,  u16* __restrict__ ws) {
  const int g = blockIdx.x * 256 + threadIdx.x;
  if (g >= NFRAG * 64) return;
  const int frag = g >> 6, lane = g & 63;
  const float* src; int K, N, kt, nt; float sgn = 1.f;
  if (frag < FW1R)       { src = w0;  K = 464; N = 160; int f = frag;       kt = f/10; nt = f%10; }
  else if (frag < FW1I)  { src = w1r; K = 144; N = 48;  int f = frag-FW1R;  kt = f/3;  nt = f%3; }
  else if (frag < FW1IN) { src = w1i; K = 144; N = 48;  int f = frag-FW1I;  kt = f/3;  nt = f%3; }
  else if (frag < FW2R)  { src = w1i; K = 144; N = 48;  int f = frag-FW1IN; kt = f/3;  nt = f%3; sgn = -1.f; }
  else if (frag < FW2I)  { src = w2r; K = 48;  N = 16;  kt = frag-FW2R; nt = 0; }
  else if (frag < FW2IN) { src = w2i; K = 48;  N = 16;  kt = frag-FW2I; nt = 0; }
  else if (frag < FL0)   { src = w2i; K = 48;  N = 16;  kt = frag-FW2IN; nt = 0; sgn = -1.f; }
  else if (frag < FL1)   { src = l0;  K = 64;  N = 64;  int f = frag-FL0;   kt = f/4;  nt = f%4; }
  else if (frag < FL2)   { src = l1;  K = 32;  N = 32;  kt = 0; nt = frag-FL1; }
  else                   { src = l2;  K = 16;  N = 16;  kt = 0; nt = 0; }
  const int n  = nt*16 + (lane & 15);
  const int k0 = kt*32 + (lane >> 4) * 8;
  u16* dst = ws + (size_t)frag * 512 + lane * 8;
  #pragma unroll
  for (int j = 0; j < 8; ++j) {
    const int k = k0 + j;
    const float v = (k < K && n < N) ? src[k * N + n] * sgn : 0.f;
    dst[j] = f2b(v);
  }
}

// ---------------- node pre-LN: f32[N][240] -> packed bf16[N][320] -------------
__global__ void ln_nodes(const float* __restrict__ rows,
                         const float* __restrict__ w0, const float* __restrict__ b0,
                         const float* __restrict__ w1, const float* __restrict__ w2,
                         u16* __restrict__ tab, int R) {
  const int row  = blockIdx.x * 4 + (threadIdx.x >> 6);
  const int lane = threadIdx.x & 63;
  if (row >= R) return;
  const float* src = rows + (size_t)row * 240;
  const float v0 = src[lane];
  const float v1 = src[lane + 64];
  const float v2 = src[lane + 128];
  const float v3 = (lane < 48) ? src[lane + 192] : 0.f;
  const bool lo = (lane < 32);
  float sm = v0, sq = v0*v0;
  float Sc = v1*v1*(1.f/192.f) + v2*v2*(lo ? (1.f/192.f) : (1.f/160.f)) + v3*v3*(1.f/160.f);
  #pragma unroll
  for (int s = 32; s > 0; s >>= 1) {
    sm += __shfl_xor(sm, s, 64); sq += __shfl_xor(sq, s, 64);
    Sc += __shfl_xor(Sc, s, 64);
  }
  const float mu  = sm * (1.f/64.f);
  const float i0  = rsqrtf(sq*(1.f/64.f) - mu*mu + 1e-8f);
  const float inv = rsqrtf(Sc + 1e-8f);
  u16* dst = tab + (size_t)row * 320;
  dst[lane] = f2b((v0 - mu) * i0 * w0[lane] + b0[lane]);
  { const int u = lane;      const int c = u/3, j = u-3*c; dst[64 + 4*c + j]  = f2b(v1*inv*w1[c]); }
  if (lo) { const int u = lane+64; const int c = u/3, j = u-3*c; dst[64 + 4*c + j]  = f2b(v2*inv*w1[c]); }
  else    { const int u = lane-32; const int c = u/5, j = u-5*c; dst[192 + 8*c + j] = f2b(v2*inv*w2[c]); }
  if (lane < 48) { const int u = lane+32; const int c = u/5, j = u-5*c; dst[192 + 8*c + j] = f2b(v3*inv*w2[c]); }
  if (lane < 32) dst[64 + 4*lane + 3] = 0;
  if (lane < 48) { const int c = lane/3, j = lane-3*c; dst[192 + 8*c + 5 + j] = 0; }
}

// ------------------------------ main fused kernel -----------------------------
// LDS layout (bytes), total 38848 -> 4 blocks/CU (8 waves each):
//  0     m0  u16[16x472+8]=15120 | o0f f32[16][172]@0 ; g1s 3x[16x40]u16 @11008
//                                | yt f32[16][64]@0 (post-B6)
//  15120 p1  u16[16x152+8]=4880  | op1f f32[16][52] ; ot f32[16][176] @15120
//  20000 n1  u16[16x152+8]=4880  | on1f
//  24880 p2  u16[16x56+8]=1808   | op2f
//  26688 n2  u16[16x56+8]=1808   | on2f
//  28496 scratch: scr f32[8][176] (phase1) | gates@28496 + scs@30032 (post-B4)
//        + g2s 5x[16x24+8]u16 @32336 (post-B5)
//  36256 Dc  f32[16x40+8]=2592
__global__ __launch_bounds__(NT, 4)
void iel_mfma(const float* __restrict__ latents,
              const float* __restrict__ edgef,
              const float* __restrict__ wig,
              const float* __restrict__ ln_e_w0, const float* __restrict__ ln_e_b0,
              const float* __restrict__ ln_e_w1, const float* __restrict__ ln_e_w2,
              const float* __restrict__ lp_b0,
              const int* __restrict__ edge_index, const int* __restrict__ active_edges,
              const u16* __restrict__ ws, const u16* __restrict__ nls,
              float* __restrict__ out,
              int Etot, int A)
{
  __shared__ __align__(16) char SMEM[38848];
  u16*   m0   = (u16*)(SMEM);
  u16*   p1   = (u16*)(SMEM + 15120);
  u16*   n1   = (u16*)(SMEM + 20000);
  u16*   p2   = (u16*)(SMEM + 24880);
  u16*   n2   = (u16*)(SMEM + 26688);
  float* scr  = (float*)(SMEM + 28496);
  float* Dc   = (float*)(SMEM + 36256);
  u16*   g2s  = (u16*)(SMEM + 32336);
  float* o0f  = (float*)(SMEM);           // stride 172
  u16*   g1s  = (u16*)(SMEM + 11008);
  float* op1f = (float*)(SMEM + 15120);
  float* on1f = (float*)(SMEM + 20000);
  float* op2f = (float*)(SMEM + 24880);
  float* on2f = (float*)(SMEM + 26688);
  u16*   gates= (u16*)(SMEM + 28496);
  u16*   scs  = (u16*)(SMEM + 30032);
  float* ot   = (float*)(SMEM + 15120);
  float* yt   = (float*)(SMEM);

  const short8* WF = (const short8*)ws;
  const int t    = threadIdx.x;
  const int lane = t & 63;
  const int w    = t >> 6;                // 0..7
  const int eb0  = blockIdx.x * EB;
  const f32x4 Z4 = {0.f, 0.f, 0.f, 0.f};

  // ---- lane class: 0 = l1 triple, 1 = l2 quint i=0..2, 2 = quint i=3..4
  const int cls = (lane < 32) ? 0 : ((lane < 48) ? 1 : 2);
  const int cc  = (cls == 0) ? lane : (lane & 15);
  const int dbase = (cls == 0) ? 1 : ((cls == 1) ? 12 : 27);
  const int dstr  = (cls == 0) ? 3 : 5;

  // ---- edge-LN staging factors ----
  const int c1 = lane / 3;
  const bool q2lo = (lane < 32);
  const int c2 = q2lo ? (lane + 64) / 3 : (lane - 32) / 5;
  const int c3 = (lane < 48) ? (lane + 32) / 5 : 15;
  const float w0e = ln_e_w0[lane], b0e = ln_e_b0[lane];
  const float wAe = ln_e_w1[c1];
  const float wBe = q2lo ? ln_e_w1[c2] : ln_e_w2[c2];
  const float wCe = ln_e_w2[c3];
  float* swr = scr + w * 176;

  // ---- edge index prefetch (wave's 2 edges) ----
  int aev[2], ecv[2], env[2];
  #pragma unroll
  for (int it = 0; it < 2; ++it) {
    const int e = eb0 + (w<<1) + it;
    aev[it] = active_edges[(e < A) ? e : (A-1)];
  }
  #pragma unroll
  for (int it = 0; it < 2; ++it) {
    ecv[it] = edge_index[aev[it]];
    env[it] = edge_index[Etot + aev[it]];
  }

  struct ER {
    u16 q0a, q0b, x4a, x4b;
    sv4 xa, xb;
    float e0, e1, e2, e3, l0, l1;
  };
  ER RA, RB;
  const int xoff = (cls == 0) ? (64 + 4*lane) : (192 + 8*cc);

  auto issue = [&](int it, ER& R) {
    const int e  = eb0 + (w<<1) + it;
    const int eS = (e < A) ? e : (A-1);
    const u16* nba = nls + (size_t)ecv[it]*320;
    const u16* nbb = nls + (size_t)env[it]*320;
    R.q0a = nba[lane]; R.q0b = nbb[lane];
    R.xa = ld4(nba + xoff); R.xb = ld4(nbb + xoff);
    R.x4a = (cls == 0) ? (u16)0 : nba[xoff + 4];
    R.x4b = (cls == 0) ? (u16)0 : nbb[xoff + 4];
    const float* ep = edgef + (size_t)eS*240;
    R.e0 = ep[lane]; R.e1 = ep[lane+64]; R.e2 = ep[lane+128];
    R.e3 = (lane < 48) ? ep[lane+192] : 0.f;
    const float* lr = latents + (size_t)aev[it]*128;
    R.l0 = lr[lane]; R.l1 = lr[64+lane];
  };

  // ---- ISSUE FIRST: get the deep gather chain in flight ----
  issue(0, RA);
  issue(1, RB);

  // ---- pad/tail clear while gathers are in flight ----
  if (t < 256) {
    const int r = t >> 4, c = t & 15;
    if (c < 8) {
      m0[r*472 + 464 + c] = 0;
      p1[r*152 + 144 + c] = 0;
      n1[r*152 + 144 + c] = 0;
      p2[r*56  + 48  + c] = 0;
      n2[r*56  + 48  + c] = 0;
    }
    if (t < 8) {
      m0[16*472 + t] = 0;
      p1[16*152 + t] = 0;
      n1[16*152 + t] = 0;
      p2[16*56  + t] = 0;
      n2[16*56  + t] = 0;
    }
  }

  // ---- stage compact Wigner D (stride 40); zero slots 10/11 -----------------
  #pragma unroll
  for (int it = 0; it < 2; ++it) {
    const int el = (w<<1) + it;
    const int e  = eb0 + el;
    const int eS = (e < A) ? e : (A-1);
    if (lane < 35) {
      int src, dst;
      if (lane == 0)      { src = 0; dst = 0; }
      else if (lane < 10) { const int a=(lane-1)/3, b=(lane-1)-3*((lane-1)/3); src=(1+a)*9+(1+b); dst=lane; }
      else                { const int a=(lane-10)/5, b=(lane-10)-5*((lane-10)/5); src=(4+a)*9+(4+b); dst=lane+2; }
      Dc[el*40 + dst] = wig[(size_t)eS*81 + src];
    } else if (lane < 37) {
      Dc[el*40 + (lane - 25)] = 0.f;   // slots 10,11 (x-padding, must be 0.0)
    }
  }

  auto process = [&](int it, ER& R) {
    const int el = (w<<1) + it;
    const float* DcE = Dc + el*40;
    const float d00 = DcE[0];
    float d[3][5];
    #pragma unroll
    for (int i = 0; i < 3; ++i)
      #pragma unroll
      for (int j = 0; j < 5; ++j)
        d[i][j] = DcE[dbase + i*dstr + j];

    u16* B0; u16* B1; u16* B2; int S0, S1, S2;
    if (cls == 0)      { B0 = n1 + el*152 + cc;      S0 = 48;  B1 = m0 + el*472 + 64 + cc; S1 = 112; B2 = p1 + el*152 + cc;      S2 = 48; }
    else if (cls == 1) { B0 = n2 + el*56  + cc;      S0 = 16;  B1 = n1 + el*152 + 32 + cc; S1 = 48;  B2 = m0 + el*472 + 96 + cc; S2 = 112; }
    else               { B0 = p1 + el*152 + 32 + cc; S0 = 48;  B1 = p2 + el*56  + cc;      S1 = 16;  B2 = m0;                    S2 = 0; }

    // node rows r=0 (ec) and r=2 (en) — paired via packed f32x2 math
    {
      f32x2 x0 = {b2f((u16)R.xa[0]), b2f((u16)R.xb[0])};
      f32x2 x1 = {b2f((u16)R.xa[1]), b2f((u16)R.xb[1])};
      f32x2 x2 = {b2f((u16)R.xa[2]), b2f((u16)R.xb[2])};
      f32x2 x3 = {b2f((u16)R.xa[3]), b2f((u16)R.xb[3])};
      f32x2 x4 = {b2f(R.x4a), b2f(R.x4b)};
      f32x2 q0 = {b2f(R.q0a), b2f(R.q0b)};
      f32x2 q0d = q0 * d00;
      m0[el*472 + lane]       = f2b(q0d[0]);
      m0[el*472 + 224 + lane] = f2b(q0d[1]);
      f32x2 s0 = x0*d[0][0] + x1*d[0][1] + x2*d[0][2] + x3*d[0][3] + x4*d[0][4];
      f32x2 s1 = x0*d[1][0] + x1*d[1][1] + x2*d[1][2] + x3*d[1][3] + x4*d[1][4];
      f32x2 s2 = x0*d[2][0] + x1*d[2][1] + x2*d[2][2] + x3*d[2][3] + x4*d[2][4];
      B0[0] = f2b(s0[0]); B0[2*S0] = f2b(s0[1]);
      B1[0] = f2b(s1[0]); B1[2*S1] = f2b(s1[1]);
      if (lane < 48) { B2[0] = f2b(s2[0]); B2[2*S2] = f2b(s2[1]); }
    }

    // edge row r=1: LN (3-sum reduction) + rotation
    {
      const float v0 = R.e0, v1 = R.e1, v2 = R.e2, v3 = R.e3;
      float sm = v0, sq = v0*v0;
      float Sc = v1*v1*(1.f/192.f) + v2*v2*(q2lo ? (1.f/192.f) : (1.f/160.f))
               + v3*v3*(1.f/160.f);
      #pragma unroll
      for (int s = 32; s > 0; s >>= 1) {
        sm += __shfl_xor(sm, s, 64);  sq += __shfl_xor(sq, s, 64);
        Sc += __shfl_xor(Sc, s, 64);
      }
      const float mu = sm * (1.f/64.f);
      const float i0 = rsqrtf(sq*(1.f/64.f) - mu*mu + 1e-8f);
      const float iv = rsqrtf(Sc + 1e-8f);
      swr[lane]      = v1 * iv * wAe;
      swr[64 + lane] = v2 * iv * wBe;
      if (lane < 48) swr[128 + lane] = v3 * iv * wCe;
      asm volatile("s_waitcnt lgkmcnt(0)" ::: "memory");
      m0[el*472 + 112 + lane] = f2b(((v0 - mu)*i0*w0e + b0e) * d00);
      const float* sb = (cls == 0) ? (swr + 3*cc) : (swr + 96 + 5*cc);
      const float x0 = sb[0], x1 = sb[1], x2 = sb[2];
      const float x3 = (cls == 0) ? 0.f : sb[3];
      const float x4 = (cls == 0) ? 0.f : sb[4];
      float s0v = d[0][0]*x0 + d[0][1]*x1 + d[0][2]*x2 + d[0][3]*x3 + d[0][4]*x4;
      float s1v = d[1][0]*x0 + d[1][1]*x1 + d[1][2]*x2 + d[1][3]*x3 + d[1][4]*x4;
      float s2v = d[2][0]*x0 + d[2][1]*x1 + d[2][2]*x2 + d[2][3]*x3 + d[2][4]*x4;
      B0[S0] = f2b(s0v);
      B1[S1] = f2b(s1v);
      if (lane < 48) B2[S2] = f2b(s2v);
    }
    m0[el*472 + 336 + lane] = f2b(R.l0);
    m0[el*472 + 400 + lane] = f2b(R.l1);
  };

  process(0, RA);
  process(1, RB);
  __syncthreads();  // B2: features + Dc ready

  // ---- Phase 2 (balanced): 2a tile w for all; extra tiles 8,9 -> waves 6,7;
  //      2b tasks -> waves 0-5; 2c tasks -> waves 0,1 ------------------------
  f32x4 acc2a[2] = {Z4, Z4};
  {
    const u16* abase = m0 + (lane & 15)*472 + (lane >> 4)*8;
    #pragma unroll
    for (int kt = 0; kt < 15; ++kt) {
      const short8 a = *reinterpret_cast<const short8*>(abase + kt*32);
      acc2a[0] = MFMA(a, WF[(size_t)(FW0 + kt*10 + w)*64 + lane], acc2a[0]);
      if (w >= 6)
        acc2a[1] = MFMA(a, WF[(size_t)(FW0 + kt*10 + (w+2))*64 + lane], acc2a[1]);
    }
  }
  f32x4 acc2b = Z4;
  f32x4 acc2c = Z4;
  if (w < 6) {
    const u16* pbase = p1 + (lane & 15)*152 + (lane >> 4)*8;
    const u16* nbase = n1 + (lane & 15)*152 + (lane >> 4)*8;
    const int isOn = (w >= 3) ? 1 : 0;
    const int nt2 = w - 3*isOn;
    #pragma unroll
    for (int kt = 0; kt < 5; ++kt) {
      const short8 pa = *reinterpret_cast<const short8*>(pbase + kt*32);
      const short8 na = *reinterpret_cast<const short8*>(nbase + kt*32);
      acc2b = MFMA(pa, WF[(size_t)((isOn?FW1I:FW1R)  + kt*3 + nt2)*64 + lane], acc2b);
      acc2b = MFMA(na, WF[(size_t)((isOn?FW1R:FW1IN) + kt*3 + nt2)*64 + lane], acc2b);
    }
  }
  if (w < 2) {
    const u16* pb2 = p2 + (lane & 15)*56 + (lane >> 4)*8;
    const u16* nb2 = n2 + (lane & 15)*56 + (lane >> 4)*8;
    const int isOn2 = (w == 1);
    #pragma unroll
    for (int kt = 0; kt < 2; ++kt) {
      const short8 pa = *reinterpret_cast<const short8*>(pb2 + kt*32);
      const short8 na = *reinterpret_cast<const short8*>(nb2 + kt*32);
      acc2c = MFMA(pa, WF[(size_t)((isOn2?FW2I:FW2R)  + kt)*64 + lane], acc2c);
      acc2c = MFMA(na, WF[(size_t)((isOn2?FW2R:FW2IN) + kt)*64 + lane], acc2c);
    }
  }
  __syncthreads();  // B3: all feature reads done

  // o0 + op/on writes (all aliasing writes in one phase)
  {
    const int col = w*16 + (lane & 15);
    const int r0  = (lane >> 4)*4;
    #pragma unroll
    for (int j = 0; j < 4; ++j)
      o0f[(r0+j)*172 + col] = acc2a[0][j] * 0.046423835f;   // 1/sqrt(464)
    if (w >= 6) {
      const int col2 = (w+2)*16 + (lane & 15);
      #pragma unroll
      for (int j = 0; j < 4; ++j)
        o0f[(r0+j)*172 + col2] = acc2a[1][j] * 0.046423835f;
    }
    if (w < 6) {
      const int isOn = (w >= 3) ? 1 : 0;
      const int nt2 = w - 3*isOn;
      float* dst = isOn ? on1f : op1f;
      const int colb = nt2*16 + (lane & 15);
      #pragma unroll
      for (int j = 0; j < 4; ++j)
        dst[(r0+j)*52 + colb] = acc2b[j] * (1.f/12.f);
    }
    if (w < 2) {
      float* dst = (w == 1) ? on2f : op2f;
      #pragma unroll
      for (int j = 0; j < 4; ++j)
        dst[(r0+j)*20 + (lane & 15)] = acc2c[j] * 0.14433757f;  // 1/sqrt(48)
    }
  }
  __syncthreads();  // B4: o0/op/on ready (scr dead from here)

  // A1 (silu/gates) + g2s pad clear
  {
    const int e = t >> 5, l32 = t & 31;
    const float d0 = Dc[e*40];
    #pragma unroll
    for (int k = 0; k < 4; ++k) {
      const int p = l32 + 32*k;
      if (p < 112) {
        const float x = o0f[e*172 + p] * d0;
        const float sg = 1.f/(1.f + __expf(-x));
        if (p < 64) scs[e*72 + p] = f2b(x * sg);
        else        gates[e*48 + (p - 64)] = f2b(sg);
      }
    }
  }
  if (t < 256) {
    const int r = t >> 4, c = t & 15;
    if (c < 8) {
      #pragma unroll
      for (int m = 0; m < 5; ++m) g2s[m*392 + r*24 + 16 + c] = 0;
    }
    if (t < 8) {
      #pragma unroll
      for (int m = 0; m < 5; ++m) g2s[m*392 + 384 + t] = 0;
    }
  }
  __syncthreads();  // B5

  // A2: rotate-back + gate -> g1/g2 bf16 staging
  {
    const int e = t >> 5, l32 = t & 31;
    const float* DcE = Dc + e*40;
    #pragma unroll
    for (int k = 0; k < 3; ++k) {
      const int item = l32 + 32*k;            // 0..95
      const int c = item/3, m = item - 3*c;
      const float val = DcE[1 + m]     * on1f[e*52 + c]
                      + DcE[1 + 3 + m] * o0f[e*172 + 112 + c]
                      + DcE[1 + 6 + m] * op1f[e*52 + c];
      const float g = b2f(gates[e*48 + c]);
      g1s[m*640 + e*40 + c] = f2b(val * g);
    }
    if (l32 < 16) {
      const int c = l32;
      const float f0 = on2f[e*20 + c];
      const float f1 = on1f[e*52 + 32 + c];
      const float f2c = o0f[e*172 + 144 + c];
      const float f3 = op1f[e*52 + 32 + c];
      const float f4 = op2f[e*20 + c];
      const float gg = b2f(gates[e*48 + 32 + c]);
      #pragma unroll
      for (int m = 0; m < 5; ++m) {
        const float val = DcE[12 + m]*f0 + DcE[12 + 5 + m]*f1 + DcE[12 + 10 + m]*f2c
                        + DcE[12 + 15 + m]*f3 + DcE[12 + 20 + m]*f4;
        g2s[m*392 + e*24 + c] = f2b(val * gg);
      }
    }
  }
  __syncthreads();  // B6 (o0f dead -> yt alias valid)

  // ---- Phase 3: final matmuls; all outputs staged (yt + ot) ------------------
  for (int tau = w; tau < 15; tau += 8) {
    const int col16 = lane & 15;
    const int r0 = (lane >> 4)*4;
    if (tau < 4) {            // y0 -> yt cols [0,64)
      const int ntt = tau;
      f32x4 a0 = Z4;
      #pragma unroll
      for (int kt = 0; kt < 2; ++kt) {
        const short8 a = *reinterpret_cast<const short8*>(
            scs + (lane & 15)*72 + kt*32 + (lane >> 4)*8);
        a0 = MFMA(a, WF[(size_t)(FL0 + kt*4 + ntt)*64 + lane], a0);
      }
      const int col = ntt*16 + col16;
      const float bias = lp_b0[col];
      #pragma unroll
      for (int j = 0; j < 4; ++j)
        yt[(r0+j)*64 + col] = a0[j]*0.125f + bias;
    } else if (tau < 10) {    // y1 -> ot cols [0,96)
      const int u = tau - 4, m = u >> 1, ntt = u & 1;
      const short8 a = *reinterpret_cast<const short8*>(
          g1s + m*640 + (lane & 15)*40 + (lane >> 4)*8);
      f32x4 a0 = Z4;
      a0 = MFMA(a, WF[(size_t)(FL1 + ntt)*64 + lane], a0);
      const int oc = (ntt*16 + col16)*3 + m;
      #pragma unroll
      for (int j = 0; j < 4; ++j)
        ot[(r0+j)*176 + oc] = a0[j]*0.17677670f;   // 1/sqrt(32)
    } else {                  // y2 -> ot cols [96,176)
      const int m = tau - 10;
      const short8 a = *reinterpret_cast<const short8*>(
          g2s + m*392 + (lane & 15)*24 + (lane >> 4)*8);
      f32x4 a0 = Z4;
      a0 = MFMA(a, WF[(size_t)FL2*64 + lane], a0);
      const int oc = 96 + col16*5 + m;
      #pragma unroll
      for (int j = 0; j < 4; ++j)
        ot[(r0+j)*176 + oc] = a0[j]*0.25f;         // 1/sqrt(16)
    }
  }
  __syncthreads();  // B7: yt + ot complete

  // single-pass coalesced copy-out: full 240-float rows (60 float4 per row)
  for (int idx = t; idx < 16*60; idx += NT) {
    const int row = idx / 60, seg = idx - row*60;
    const int er = eb0 + row;
    if (er < A) {
      f32x4 v;
      if (seg < 16) v = *reinterpret_cast<const f32x4*>(yt + row*64 + seg*4);
      else          v = *reinterpret_cast<const f32x4*>(ot + row*176 + (seg-16)*4);
      *reinterpret_cast<f32x4*>(out + (size_t)er*240 + seg*4) = v;
    }
  }
}

extern "C" void kernel_launch(void* const* d_in, const int* in_sizes, int n_in,
                              void* d_out, int out_size, void* d_ws, size_t ws_size,
                              hipStream_t stream) {
  const float* latents  = (const float*)d_in[0];
  const float* nodef    = (const float*)d_in[1];
  const float* edgef    = (const float*)d_in[2];
  const float* wig      = (const float*)d_in[4];
  const float* ln_n_w0  = (const float*)d_in[5];
  const float* ln_n_b0  = (const float*)d_in[6];
  const float* ln_n_w1  = (const float*)d_in[7];
  const float* ln_n_w2  = (const float*)d_in[8];
  const float* ln_e_w0  = (const float*)d_in[9];
  const float* ln_e_b0  = (const float*)d_in[10];
  const float* ln_e_w1  = (const float*)d_in[11];
  const float* ln_e_w2  = (const float*)d_in[12];
  const float* so2_w0   = (const float*)d_in[13];
  const float* so2_w1r  = (const float*)d_in[14];
  const float* so2_w1i  = (const float*)d_in[15];
  const float* so2_w2r  = (const float*)d_in[16];
  const float* so2_w2i  = (const float*)d_in[17];
  const float* lp_w0    = (const float*)d_in[18];
  const float* lp_b0    = (const float*)d_in[19];
  const float* lp_w1    = (const float*)d_in[20];
  const float* lp_w2    = (const float*)d_in[21];
  const int*   edge_index   = (const int*)d_in[22];
  const int*   active_edges = (const int*)d_in[23];

  const int Etot = in_sizes[2] / 240;
  const int N    = in_sizes[1] / 240;
  const int A    = in_sizes[23];

  u16* ws  = (u16*)d_ws;
  u16* nls = ws + WS_NLS_OFF;            // node-LN table: N*320 u16

  const int pthreads = NFRAG * 64;
  hipLaunchKernelGGL(prep_w, dim3((pthreads + 255) / 256), dim3(256), 0, stream,
                     so2_w0, so2_w1r, so2_w1i, so2_w2r, so2_w2i,
                     lp_w0, lp_w1, lp_w2, ws);

  hipLaunchKernelGGL(ln_nodes, dim3((N + 3) / 4), dim3(256), 0, stream,
                     nodef, ln_n_w0, ln_n_b0, ln_n_w1, ln_n_w2, nls, N);

  const int grid = (A + EB - 1) / EB;
  hipLaunchKernelGGL(iel_mfma, dim3(grid), dim3(NT), 0, stream,
                     latents, edgef, wig,
                     ln_e_w0, ln_e_b0, ln_e_w1, ln_e_w2,
                     lp_b0, edge_index, active_edges, ws, nls,
                     (float*)d_out, Etot, A);
}